// Round 1
// baseline (383.356 us; speedup 1.0000x reference)
//
#include <hip/hip_runtime.h>
#include <hip/hip_bf16.h>
#include <math.h>

#define LA 1536
#define LS 512
#define LT 2048
#define CC 256
#define NH 4
#define DKH 64
#define NB 4

// ---------------------------------------------------------------------------
// Kernel 1: fused QKV projection.  out[m,n] = sum_k x[m,k] * W[n,k] + bias[n]
// x = concat(audio, text) along seq (virtual). M = 8192, N = 768 (Wq|Wk|Wv), K = 256.
// 64x64 block tile, 256 threads, 4x4 per-thread micro-tile, transposed LDS.
// ---------------------------------------------------------------------------
__global__ __launch_bounds__(256) void qkv_gemm(
    const float* __restrict__ audio, const float* __restrict__ text,
    const float* __restrict__ Wq, const float* __restrict__ bq,
    const float* __restrict__ Wk, const float* __restrict__ bk,
    const float* __restrict__ Wv, const float* __restrict__ bv,
    float* __restrict__ Q, float* __restrict__ K, float* __restrict__ V)
{
    __shared__ float As[64][68];  // [k][m]
    __shared__ float Bs[64][68];  // [k][n]

    const int tid = threadIdx.x;
    const int ty = tid >> 4;   // 0..15
    const int tx = tid & 15;   // 0..15

    const int m0 = blockIdx.x * 64;
    const int n0 = blockIdx.y * 64;      // 0..767 in steps of 64
    const int mat = n0 >> 8;             // 0=Q, 1=K, 2=V
    const int ch0 = n0 & 255;

    const float* W    = (mat == 0) ? Wq : (mat == 1) ? Wk : Wv;
    const float* bias = (mat == 0) ? bq : (mat == 1) ? bk : bv;
    float*       Out  = (mat == 0) ? Q  : (mat == 1) ? K  : V;

    const int b  = m0 >> 11;     // 2048 rows per batch; 64-tiles never straddle
    const int l0 = m0 & 2047;    // 1536 is 64-aligned -> audio/text split clean

    float acc[4][4] = {};

    for (int k0 = 0; k0 < CC; k0 += 64) {
        #pragma unroll
        for (int rr = 0; rr < 4; ++rr) {
            const int row = rr * 16 + ty;
            const int col = tx * 4;
            const int l = l0 + row;
            const float* src = (l < LA)
                ? (audio + ((size_t)b * LA + l) * CC + k0 + col)
                : (text  + ((size_t)b * LS + (l - LA)) * CC + k0 + col);
            const float4 a4 = *(const float4*)src;
            As[col + 0][row] = a4.x;
            As[col + 1][row] = a4.y;
            As[col + 2][row] = a4.z;
            As[col + 3][row] = a4.w;
            const float4 w4 = *(const float4*)(W + (size_t)(ch0 + row) * CC + k0 + col);
            Bs[col + 0][row] = w4.x;
            Bs[col + 1][row] = w4.y;
            Bs[col + 2][row] = w4.z;
            Bs[col + 3][row] = w4.w;
        }
        __syncthreads();
        #pragma unroll 8
        for (int kk = 0; kk < 64; ++kk) {
            const float4 a4 = *(const float4*)&As[kk][ty * 4];
            const float4 w4 = *(const float4*)&Bs[kk][tx * 4];
            const float a[4] = {a4.x, a4.y, a4.z, a4.w};
            const float w[4] = {w4.x, w4.y, w4.z, w4.w};
            #pragma unroll
            for (int i = 0; i < 4; ++i)
                #pragma unroll
                for (int j = 0; j < 4; ++j)
                    acc[i][j] += a[i] * w[j];
        }
        __syncthreads();
    }

    const int nq = ch0 + tx * 4;
    const float4 b4 = *(const float4*)(bias + nq);
    const float bb[4] = {b4.x, b4.y, b4.z, b4.w};
    #pragma unroll
    for (int i = 0; i < 4; ++i) {
        const int m = m0 + ty * 4 + i;
        const float4 o4 = make_float4(acc[i][0] + bb[0], acc[i][1] + bb[1],
                                      acc[i][2] + bb[2], acc[i][3] + bb[3]);
        *(float4*)(Out + (size_t)m * CC + nq) = o4;
    }
}

// ---------------------------------------------------------------------------
// Kernel 2: flash attention, fp32, with the INVERTED mask.
// allowed(q,k):  k<LA: k >= ilen ;  k>=LA: (q<LA) || (k>q) || (k >= LA+ylen)
// One block = 64 queries of one (b,h). 32 key-tiles of 64. Online softmax.
// S^T aliased into the K^T buffer (saves 17 KB LDS -> 3 blocks/CU).
// ---------------------------------------------------------------------------
__global__ __launch_bounds__(256) void attn_fp32(
    const float* __restrict__ Q, const float* __restrict__ K,
    const float* __restrict__ V,
    const int* __restrict__ slen, const int* __restrict__ tlen,
    float* __restrict__ AO)
{
    __shared__ float Qt[64][68];    // [d][r]
    __shared__ float KtP[64][68];   // [d][key] as K^T; reused as P^T [key][r]
    __shared__ float Vs[64][68];    // [key][d]
    __shared__ float m_sm[64], l_sm[64], sc_sm[64];

    const int tid = threadIdx.x;
    const int ty = tid >> 4, tx = tid & 15;

    const int q0 = blockIdx.x * 64;
    const int h  = blockIdx.y;
    const int b  = blockIdx.z;

    const int ilen = slen[b];
    const int kcap = LA + tlen[b];

    #pragma unroll
    for (int rr = 0; rr < 4; ++rr) {
        const int row = rr * 16 + ty;
        const int col = tx * 4;
        const float4 q4 = *(const float4*)(Q + ((size_t)b * LT + q0 + row) * CC + h * DKH + col);
        Qt[col + 0][row] = q4.x;
        Qt[col + 1][row] = q4.y;
        Qt[col + 2][row] = q4.z;
        Qt[col + 3][row] = q4.w;
    }
    if (tid < 64) { m_sm[tid] = -INFINITY; l_sm[tid] = 0.0f; }

    float o[4][4] = {};

    for (int kt = 0; kt < LT / 64; ++kt) {
        const int k0 = kt * 64;
        __syncthreads();  // prev-iter readers of KtP/Vs done; Qt/m_sm init done
        #pragma unroll
        for (int rr = 0; rr < 4; ++rr) {
            const int row = rr * 16 + ty;   // key within tile
            const int col = tx * 4;         // d
            const size_t base = ((size_t)b * LT + k0 + row) * CC + h * DKH + col;
            const float4 k4 = *(const float4*)(K + base);
            KtP[col + 0][row] = k4.x;
            KtP[col + 1][row] = k4.y;
            KtP[col + 2][row] = k4.z;
            KtP[col + 3][row] = k4.w;
            *(float4*)&Vs[row][col] = *(const float4*)(V + base);
        }
        __syncthreads();

        // S = Q K^T (thread owns rows 4ty+i, keys 4tx+j)
        float s[4][4] = {};
        #pragma unroll 8
        for (int d = 0; d < 64; ++d) {
            const float4 a4 = *(const float4*)&Qt[d][ty * 4];
            const float4 k4 = *(const float4*)&KtP[d][tx * 4];
            const float a[4] = {a4.x, a4.y, a4.z, a4.w};
            const float kkv[4] = {k4.x, k4.y, k4.z, k4.w};
            #pragma unroll
            for (int i = 0; i < 4; ++i)
                #pragma unroll
                for (int j = 0; j < 4; ++j)
                    s[i][j] += a[i] * kkv[j];
        }
        __syncthreads();  // all K reads complete; KtP now becomes P^T

        #pragma unroll
        for (int j = 0; j < 4; ++j) {
            const int kk_ = k0 + tx * 4 + j;
            const bool kallow_a = (kk_ >= ilen);
            #pragma unroll
            for (int i = 0; i < 4; ++i) {
                const int qq = q0 + ty * 4 + i;
                const bool allowed = (kk_ < LA)
                    ? kallow_a
                    : (qq < LA || kk_ > qq || kk_ >= kcap);
                KtP[tx * 4 + j][ty * 4 + i] = allowed ? s[i][j] * 0.125f : -INFINITY;
            }
        }
        __syncthreads();

        // online softmax: 4 threads per row (wave-parallel, shfl_xor groups)
        {
            const int r = tid >> 2;
            const int c = tid & 3;
            float vals[16];
            float mloc = -INFINITY;
            #pragma unroll
            for (int u = 0; u < 16; ++u) {
                vals[u] = KtP[c * 16 + u][r];
                mloc = fmaxf(mloc, vals[u]);
            }
            mloc = fmaxf(mloc, __shfl_xor(mloc, 1));
            mloc = fmaxf(mloc, __shfl_xor(mloc, 2));
            const float m_old = m_sm[r];
            const float m_new = fmaxf(m_old, mloc);
            if (m_new == -INFINITY) {   // whole tile masked for this row
                #pragma unroll
                for (int u = 0; u < 16; ++u) KtP[c * 16 + u][r] = 0.0f;
                if (c == 0) sc_sm[r] = 1.0f;
            } else {
                float ssum = 0.0f;
                #pragma unroll
                for (int u = 0; u < 16; ++u) {
                    const float p = __expf(vals[u] - m_new);  // exp(-inf)=0
                    KtP[c * 16 + u][r] = p;
                    ssum += p;
                }
                ssum += __shfl_xor(ssum, 1);
                ssum += __shfl_xor(ssum, 2);
                if (c == 0) {
                    const float sc = __expf(m_old - m_new);   // m_old=-inf -> 0
                    sc_sm[r] = sc;
                    l_sm[r] = l_sm[r] * sc + ssum;
                    m_sm[r] = m_new;
                }
            }
        }
        __syncthreads();

        // rescale O, accumulate P·V
        float scr[4];
        #pragma unroll
        for (int i = 0; i < 4; ++i) scr[i] = sc_sm[ty * 4 + i];
        #pragma unroll
        for (int i = 0; i < 4; ++i)
            #pragma unroll
            for (int j = 0; j < 4; ++j)
                o[i][j] *= scr[i];
        #pragma unroll 8
        for (int k = 0; k < 64; ++k) {
            const float4 p4 = *(const float4*)&KtP[k][ty * 4];
            const float4 v4 = *(const float4*)&Vs[k][tx * 4];
            const float p[4] = {p4.x, p4.y, p4.z, p4.w};
            const float vv[4] = {v4.x, v4.y, v4.z, v4.w};
            #pragma unroll
            for (int i = 0; i < 4; ++i)
                #pragma unroll
                for (int j = 0; j < 4; ++j)
                    o[i][j] += p[i] * vv[j];
        }
    }

    #pragma unroll
    for (int i = 0; i < 4; ++i) {
        const int r = ty * 4 + i;
        const float inv = 1.0f / l_sm[r];     // every row has >=1 allowed key
        const float4 o4 = make_float4(o[i][0] * inv, o[i][1] * inv,
                                      o[i][2] * inv, o[i][3] * inv);
        *(float4*)(AO + ((size_t)b * LT + q0 + r) * CC + h * DKH + tx * 4) = o4;
    }
}

// ---------------------------------------------------------------------------
// Kernel 3: output projection.  out[m,n] = sum_k X[m,k] * Wo[n,k] + bo[n]
// ---------------------------------------------------------------------------
__global__ __launch_bounds__(256) void out_gemm(
    const float* __restrict__ X, const float* __restrict__ Wo,
    const float* __restrict__ bo, float* __restrict__ Out)
{
    __shared__ float As[64][68];
    __shared__ float Bs[64][68];

    const int tid = threadIdx.x;
    const int ty = tid >> 4, tx = tid & 15;
    const int m0 = blockIdx.x * 64;
    const int n0 = blockIdx.y * 64;

    float acc[4][4] = {};

    for (int k0 = 0; k0 < CC; k0 += 64) {
        #pragma unroll
        for (int rr = 0; rr < 4; ++rr) {
            const int row = rr * 16 + ty;
            const int col = tx * 4;
            const float4 a4 = *(const float4*)(X + (size_t)(m0 + row) * CC + k0 + col);
            As[col + 0][row] = a4.x;
            As[col + 1][row] = a4.y;
            As[col + 2][row] = a4.z;
            As[col + 3][row] = a4.w;
            const float4 w4 = *(const float4*)(Wo + (size_t)(n0 + row) * CC + k0 + col);
            Bs[col + 0][row] = w4.x;
            Bs[col + 1][row] = w4.y;
            Bs[col + 2][row] = w4.z;
            Bs[col + 3][row] = w4.w;
        }
        __syncthreads();
        #pragma unroll 8
        for (int kk = 0; kk < 64; ++kk) {
            const float4 a4 = *(const float4*)&As[kk][ty * 4];
            const float4 w4 = *(const float4*)&Bs[kk][tx * 4];
            const float a[4] = {a4.x, a4.y, a4.z, a4.w};
            const float w[4] = {w4.x, w4.y, w4.z, w4.w};
            #pragma unroll
            for (int i = 0; i < 4; ++i)
                #pragma unroll
                for (int j = 0; j < 4; ++j)
                    acc[i][j] += a[i] * w[j];
        }
        __syncthreads();
    }

    const int nq = n0 + tx * 4;
    const float4 b4 = *(const float4*)(bo + nq);
    const float bb[4] = {b4.x, b4.y, b4.z, b4.w};
    #pragma unroll
    for (int i = 0; i < 4; ++i) {
        const int m = m0 + ty * 4 + i;
        const float4 o4 = make_float4(acc[i][0] + bb[0], acc[i][1] + bb[1],
                                      acc[i][2] + bb[2], acc[i][3] + bb[3]);
        *(float4*)(Out + (size_t)m * CC + nq) = o4;
    }
}

// ---------------------------------------------------------------------------
extern "C" void kernel_launch(void* const* d_in, const int* in_sizes, int n_in,
                              void* d_out, int out_size, void* d_ws, size_t ws_size,
                              hipStream_t stream)
{
    const float* audio = (const float*)d_in[0];
    const float* text  = (const float*)d_in[1];
    const int*   slen  = (const int*)d_in[2];
    const int*   tlen  = (const int*)d_in[3];
    const float* Wq = (const float*)d_in[4];
    const float* bq = (const float*)d_in[5];
    const float* Wk = (const float*)d_in[6];
    const float* bk = (const float*)d_in[7];
    const float* Wv = (const float*)d_in[8];
    const float* bv = (const float*)d_in[9];
    const float* Wo = (const float*)d_in[10];
    const float* bo = (const float*)d_in[11];
    float* out = (float*)d_out;

    // workspace: Q,K,V,attn_out, each [B*L, C] fp32 = 8 MB -> 32 MB total
    const size_t SZ = (size_t)NB * LT * CC;
    float* Qw = (float*)d_ws;
    float* Kw = Qw + SZ;
    float* Vw = Kw + SZ;
    float* AO = Vw + SZ;

    qkv_gemm<<<dim3(128, 12), 256, 0, stream>>>(audio, text, Wq, bq, Wk, bk, Wv, bv,
                                                Qw, Kw, Vw);
    attn_fp32<<<dim3(LT / 64, NH, NB), 256, 0, stream>>>(Qw, Kw, Vw, slen, tlen, AO);
    out_gemm<<<dim3(128, 4), 256, 0, stream>>>(AO, Wo, bo, out);
}

// Round 2
// 180.627 us; speedup vs baseline: 2.1224x; 2.1224x over previous
//
#include <hip/hip_runtime.h>
#include <hip/hip_bf16.h>
#include <math.h>

#define LA 1536
#define LS 512
#define LT 2048
#define CC 256
#define NH 4
#define DKH 64
#define NB 4

typedef _Float16 f16;
typedef __attribute__((ext_vector_type(8))) _Float16 f16x8;
typedef __attribute__((ext_vector_type(4))) _Float16 f16x4;
typedef __attribute__((ext_vector_type(4))) float f32x4;

// ---------------------------------------------------------------------------
// Kernel 1: fused QKV projection (fp32 accumulate), fp16 outputs.
// Q,K row-major [B*L][C] fp16.  V written TRANSPOSED: Vt[(b*NH+h)*DKH+d][L] fp16
// so the attention PV B-operand is a contiguous LDS read.
// ---------------------------------------------------------------------------
__global__ __launch_bounds__(256) void qkv_gemm(
    const float* __restrict__ audio, const float* __restrict__ text,
    const float* __restrict__ Wq, const float* __restrict__ bq,
    const float* __restrict__ Wk, const float* __restrict__ bk,
    const float* __restrict__ Wv, const float* __restrict__ bv,
    f16* __restrict__ Qh, f16* __restrict__ Kh, f16* __restrict__ Vth)
{
    __shared__ float As[64][68];  // [k][m]
    __shared__ float Bs[64][68];  // [k][n]

    const int tid = threadIdx.x;
    const int ty = tid >> 4;   // 0..15
    const int tx = tid & 15;   // 0..15

    const int m0 = blockIdx.x * 64;
    const int n0 = blockIdx.y * 64;      // 0..767
    const int mat = n0 >> 8;             // 0=Q, 1=K, 2=V
    const int ch0 = n0 & 255;

    const float* W    = (mat == 0) ? Wq : (mat == 1) ? Wk : Wv;
    const float* bias = (mat == 0) ? bq : (mat == 1) ? bk : bv;

    const int b  = m0 >> 11;
    const int l0 = m0 & 2047;

    float acc[4][4] = {};

    for (int k0 = 0; k0 < CC; k0 += 64) {
        #pragma unroll
        for (int rr = 0; rr < 4; ++rr) {
            const int row = rr * 16 + ty;
            const int col = tx * 4;
            const int l = l0 + row;
            const float* src = (l < LA)
                ? (audio + ((size_t)b * LA + l) * CC + k0 + col)
                : (text  + ((size_t)b * LS + (l - LA)) * CC + k0 + col);
            const float4 a4 = *(const float4*)src;
            As[col + 0][row] = a4.x;
            As[col + 1][row] = a4.y;
            As[col + 2][row] = a4.z;
            As[col + 3][row] = a4.w;
            const float4 w4 = *(const float4*)(W + (size_t)(ch0 + row) * CC + k0 + col);
            Bs[col + 0][row] = w4.x;
            Bs[col + 1][row] = w4.y;
            Bs[col + 2][row] = w4.z;
            Bs[col + 3][row] = w4.w;
        }
        __syncthreads();
        #pragma unroll 8
        for (int kk = 0; kk < 64; ++kk) {
            const float4 a4 = *(const float4*)&As[kk][ty * 4];
            const float4 w4 = *(const float4*)&Bs[kk][tx * 4];
            const float a[4] = {a4.x, a4.y, a4.z, a4.w};
            const float w[4] = {w4.x, w4.y, w4.z, w4.w};
            #pragma unroll
            for (int i = 0; i < 4; ++i)
                #pragma unroll
                for (int j = 0; j < 4; ++j)
                    acc[i][j] += a[i] * w[j];
        }
        __syncthreads();
    }

    const int nq = ch0 + tx * 4;
    const float4 b4 = *(const float4*)(bias + nq);
    const float bb[4] = {b4.x, b4.y, b4.z, b4.w};

    if (mat <= 1) {
        f16* Out = (mat == 0) ? Qh : Kh;
        #pragma unroll
        for (int i = 0; i < 4; ++i) {
            const int m = m0 + ty * 4 + i;
            f16x4 h4;
            #pragma unroll
            for (int j = 0; j < 4; ++j) h4[j] = (_Float16)(acc[i][j] + bb[j]);
            *(f16x4*)(Out + (size_t)m * CC + nq) = h4;
        }
    } else {
        // V: transposed scatter  Vt[(b*NH+h)*DKH + d][l]
        #pragma unroll
        for (int i = 0; i < 4; ++i) {
            const int m = m0 + ty * 4 + i;
            const int bb_ = m >> 11;
            const int ll  = m & 2047;
            #pragma unroll
            for (int j = 0; j < 4; ++j) {
                const int n = nq + j;
                const int hh = n >> 6;
                const int dd = n & 63;
                Vth[((size_t)(bb_ * NH + hh) * DKH + dd) * LT + ll] =
                    (_Float16)(acc[i][j] + bb[j]);
            }
        }
    }
}

// ---------------------------------------------------------------------------
// Kernel 2: flash attention, fp16 MFMA, inverted mask.
// Block = 4 waves x 16 queries = 64 q of one (b,h); 32 key-tiles of 64.
// Swapped QK^T: S^T = mfma(A=K, B=Q) -> lane owns one q-row (q = l&15),
// softmax via shfl_xor(16/32). P re-layout through per-wave LDS buffer.
// K / Vt LDS tiles XOR-swizzled (16B-chunk ^ row&7) for conflict-free b128.
// ---------------------------------------------------------------------------
__global__ __launch_bounds__(256) void attn_f16(
    const f16* __restrict__ Q, const f16* __restrict__ K,
    const f16* __restrict__ Vt,
    const int* __restrict__ slen, const int* __restrict__ tlen,
    float* __restrict__ AO)
{
    __shared__ f16 Ks[64 * 64];       // [key][d], swizzled
    __shared__ f16 Vts[64 * 64];      // [d][key], swizzled
    __shared__ f16 Ps[4][16 * 72];    // per-wave P [q_local][kk], stride 72

    const int tid = threadIdx.x;
    const int w = tid >> 6;
    const int l = tid & 63;
    const int g = l >> 4;     // quarter
    const int r = l & 15;

    const int q0 = blockIdx.x * 64;
    const int h  = blockIdx.y;
    const int b  = blockIdx.z;

    const int ilen = slen[b];
    const int kcap = LA + tlen[b];

    const int qrow = q0 + 16 * w + r;     // this lane's q (softmax layout)

    // Q fragments, held in registers for the whole kernel.
    // B-frag for mfma(K,Q): lane l holds Q[q = l&15 (+16w)][d = ch*32 + 8g + e]
    f16x8 qf[2];
    #pragma unroll
    for (int ch = 0; ch < 2; ++ch)
        qf[ch] = *(const f16x8*)(Q + ((size_t)(b * LT) + qrow) * CC + h * DKH + ch * 32 + g * 8);

    float m_run = -INFINITY, l_run = 0.0f;
    f32x4 o[4] = {};   // o[dsub][e]: O[q = 4g+e][d = 16*dsub + r]

    for (int kt = 0; kt < LT / 64; ++kt) {
        const int k0 = kt * 64;
        __syncthreads();                       // prior-iter readers done
        #pragma unroll
        for (int m = 0; m < 2; ++m) {
            const int idx = m * 256 + tid;
            const int row = idx >> 3;
            const int c   = idx & 7;
            const int dst = row * 64 + (((c ^ (row & 7)) & 7) << 3);
            *(f16x8*)(Ks + dst) =
                *(const f16x8*)(K + ((size_t)(b * LT) + k0 + row) * CC + h * DKH + c * 8);
            *(f16x8*)(Vts + dst) =
                *(const f16x8*)(Vt + ((size_t)((b * NH + h) * DKH) + row) * LT + k0 + c * 8);
        }
        __syncthreads();

        // ---- S^T = K · Q^T : 4 kk-subtiles, K-dim d split into 2x32
        f32x4 sacc[4] = {};
        #pragma unroll
        for (int s = 0; s < 4; ++s) {
            const int row = 16 * s + r;
            #pragma unroll
            for (int ch = 0; ch < 2; ++ch) {
                const f16x8 a = *(const f16x8*)(Ks + row * 64 + ((((ch * 4 + g) ^ (row & 7)) & 7) << 3));
                sacc[s] = __builtin_amdgcn_mfma_f32_16x16x32_f16(a, qf[ch], sacc[s], 0, 0, 0);
            }
        }

        // ---- mask + online softmax. Lane owns q=qrow; kk = k0+16s+4g+e.
        float sv[4][4];
        float mloc = -INFINITY;
        #pragma unroll
        for (int s = 0; s < 4; ++s)
            #pragma unroll
            for (int e = 0; e < 4; ++e) {
                const int kk = k0 + 16 * s + 4 * g + e;
                const bool allowed = (kk < LA)
                    ? (kk >= ilen)
                    : (qrow < LA || kk > qrow || kk >= kcap);
                const float v = allowed ? sacc[s][e] * 0.125f : -INFINITY;
                sv[s][e] = v;
                mloc = fmaxf(mloc, v);
            }
        mloc = fmaxf(mloc, __shfl_xor(mloc, 16));
        mloc = fmaxf(mloc, __shfl_xor(mloc, 32));
        const float m_new = fmaxf(m_run, mloc);

        float sc;
        f16x4 ph[4];
        if (m_new == -INFINITY) {              // tile fully masked for this row
            sc = 1.0f;
            #pragma unroll
            for (int s = 0; s < 4; ++s)
                #pragma unroll
                for (int e = 0; e < 4; ++e) ph[s][e] = (_Float16)0.0f;
        } else {
            float ssum = 0.0f;
            #pragma unroll
            for (int s = 0; s < 4; ++s)
                #pragma unroll
                for (int e = 0; e < 4; ++e) {
                    const float p = __expf(sv[s][e] - m_new);   // exp(-inf)=0
                    ph[s][e] = (_Float16)p;
                    ssum += p;
                }
            ssum += __shfl_xor(ssum, 16);
            ssum += __shfl_xor(ssum, 32);
            sc = (m_run == -INFINITY) ? 0.0f : __expf(m_run - m_new);
            l_run = l_run * sc + ssum;
            m_run = m_new;
        }

        // ---- store P to per-wave LDS (packed 8B, stride-72 pad: ~no conflicts)
        #pragma unroll
        for (int s = 0; s < 4; ++s)
            *(f16x4*)(&Ps[w][0] + r * 72 + 16 * s + 4 * g) = ph[s];

        // ---- broadcast rescale to O layout (q = 4g+e) and rescale O
        #pragma unroll
        for (int e = 0; e < 4; ++e) {
            const float scr = __shfl(sc, 4 * g + e);
            #pragma unroll
            for (int dsb = 0; dsb < 4; ++dsb) o[dsb][e] *= scr;
        }

        // ---- O += P · V   (A = P from Ps, B = V from Vts, both contiguous)
        #pragma unroll
        for (int ch = 0; ch < 2; ++ch) {
            const f16x8 a = *(const f16x8*)(&Ps[w][0] + r * 72 + ch * 32 + g * 8);
            #pragma unroll
            for (int dsb = 0; dsb < 4; ++dsb) {
                const int vrow = 16 * dsb + r;
                const f16x8 bf = *(const f16x8*)(Vts + vrow * 64 + ((((ch * 4 + g) ^ (vrow & 7)) & 7) << 3));
                o[dsb] = __builtin_amdgcn_mfma_f32_16x16x32_f16(a, bf, o[dsb], 0, 0, 0);
            }
        }
    }

    // ---- epilogue: divide by l, store
    const float linv = 1.0f / l_run;
    #pragma unroll
    for (int e = 0; e < 4; ++e) {
        const float inv = __shfl(linv, 4 * g + e);
        const int qq = q0 + 16 * w + 4 * g + e;
        #pragma unroll
        for (int dsb = 0; dsb < 4; ++dsb)
            AO[((size_t)(b * LT) + qq) * CC + h * DKH + 16 * dsb + r] = o[dsb][e] * inv;
    }
}

// ---------------------------------------------------------------------------
// Kernel 3: output projection (fp32).  out[m,n] = sum_k X[m,k]*Wo[n,k] + bo[n]
// ---------------------------------------------------------------------------
__global__ __launch_bounds__(256) void out_gemm(
    const float* __restrict__ X, const float* __restrict__ Wo,
    const float* __restrict__ bo, float* __restrict__ Out)
{
    __shared__ float As[64][68];
    __shared__ float Bs[64][68];

    const int tid = threadIdx.x;
    const int ty = tid >> 4, tx = tid & 15;
    const int m0 = blockIdx.x * 64;
    const int n0 = blockIdx.y * 64;

    float acc[4][4] = {};

    for (int k0 = 0; k0 < CC; k0 += 64) {
        #pragma unroll
        for (int rr = 0; rr < 4; ++rr) {
            const int row = rr * 16 + ty;
            const int col = tx * 4;
            const float4 a4 = *(const float4*)(X + (size_t)(m0 + row) * CC + k0 + col);
            As[col + 0][row] = a4.x;
            As[col + 1][row] = a4.y;
            As[col + 2][row] = a4.z;
            As[col + 3][row] = a4.w;
            const float4 w4 = *(const float4*)(Wo + (size_t)(n0 + row) * CC + k0 + col);
            Bs[col + 0][row] = w4.x;
            Bs[col + 1][row] = w4.y;
            Bs[col + 2][row] = w4.z;
            Bs[col + 3][row] = w4.w;
        }
        __syncthreads();
        #pragma unroll 8
        for (int kk = 0; kk < 64; ++kk) {
            const float4 a4 = *(const float4*)&As[kk][ty * 4];
            const float4 w4 = *(const float4*)&Bs[kk][tx * 4];
            const float a[4] = {a4.x, a4.y, a4.z, a4.w};
            const float w[4] = {w4.x, w4.y, w4.z, w4.w};
            #pragma unroll
            for (int i = 0; i < 4; ++i)
                #pragma unroll
                for (int j = 0; j < 4; ++j)
                    acc[i][j] += a[i] * w[j];
        }
        __syncthreads();
    }

    const int nq = n0 + tx * 4;
    const float4 b4 = *(const float4*)(bo + nq);
    const float bb[4] = {b4.x, b4.y, b4.z, b4.w};
    #pragma unroll
    for (int i = 0; i < 4; ++i) {
        const int m = m0 + ty * 4 + i;
        const float4 o4 = make_float4(acc[i][0] + bb[0], acc[i][1] + bb[1],
                                      acc[i][2] + bb[2], acc[i][3] + bb[3]);
        *(float4*)(Out + (size_t)m * CC + nq) = o4;
    }
}

// ---------------------------------------------------------------------------
extern "C" void kernel_launch(void* const* d_in, const int* in_sizes, int n_in,
                              void* d_out, int out_size, void* d_ws, size_t ws_size,
                              hipStream_t stream)
{
    const float* audio = (const float*)d_in[0];
    const float* text  = (const float*)d_in[1];
    const int*   slen  = (const int*)d_in[2];
    const int*   tlen  = (const int*)d_in[3];
    const float* Wq = (const float*)d_in[4];
    const float* bq = (const float*)d_in[5];
    const float* Wk = (const float*)d_in[6];
    const float* bk = (const float*)d_in[7];
    const float* Wv = (const float*)d_in[8];
    const float* bv = (const float*)d_in[9];
    const float* Wo = (const float*)d_in[10];
    const float* bo = (const float*)d_in[11];
    float* out = (float*)d_out;

    // workspace: Qh,Kh,Vth fp16 (4 MB each) + AO fp32 (8 MB)
    const size_t SZ = (size_t)NB * LT * CC;   // 2M elements
    f16* Qh  = (f16*)d_ws;
    f16* Kh  = Qh + SZ;
    f16* Vth = Kh + SZ;
    float* AO = (float*)(Vth + SZ);

    qkv_gemm<<<dim3(128, 12), 256, 0, stream>>>(audio, text, Wq, bq, Wk, bk, Wv, bv,
                                                Qh, Kh, Vth);
    attn_f16<<<dim3(LT / 64, NH, NB), 256, 0, stream>>>(Qh, Kh, Vth, slen, tlen, AO);
    out_gemm<<<dim3(128, 4), 256, 0, stream>>>(AO, Wo, bo, out);
}

// Round 3
// 54.066 us; speedup vs baseline: 7.0905x; 3.3408x over previous
//
#include <hip/hip_runtime.h>
#include <hip/hip_bf16.h>
#include <math.h>

#define LA 1536
#define LS 512
#define LT 2048
#define CC 256
#define NH 4
#define DKH 64
#define NB 4
#define NT (LT / 64)

typedef _Float16 f16;
typedef __attribute__((ext_vector_type(8))) _Float16 f16x8;
typedef __attribute__((ext_vector_type(4))) _Float16 f16x4;
typedef __attribute__((ext_vector_type(4))) float f32x4;

__device__ inline f16x8 cvt8(const float4 a, const float4 b) {
    f16x8 h;
    h[0] = (_Float16)a.x; h[1] = (_Float16)a.y; h[2] = (_Float16)a.z; h[3] = (_Float16)a.w;
    h[4] = (_Float16)b.x; h[5] = (_Float16)b.y; h[6] = (_Float16)b.z; h[7] = (_Float16)b.w;
    return h;
}

// ---------------------------------------------------------------------------
// Kernel 1: fused QKV projection, fp16 MFMA, fp32 accumulate.
// C[m,n] = sum_k x[m,k] * W[n,k] + bias[n].  M=8192 (tile 128), N=768 (tile 64).
// Q,K row-major f16; V transposed: Vt[(b*NH+h)*DKH+d][l] f16.
// MFMA frags (verified r2): A lane l: A[row=l&15][k=8*(l>>4)+e];
// B lane l: B[k=8*(l>>4)+e][col=l&15]; C: row=4*(l>>4)+e, col=l&15.
// ---------------------------------------------------------------------------
__global__ __launch_bounds__(256) void qkv_mfma(
    const float* __restrict__ audio, const float* __restrict__ text,
    const float* __restrict__ Wq, const float* __restrict__ bq,
    const float* __restrict__ Wk, const float* __restrict__ bk,
    const float* __restrict__ Wv, const float* __restrict__ bv,
    f16* __restrict__ Qh, f16* __restrict__ Kh, f16* __restrict__ Vth)
{
    __shared__ f16 As[128 * 64];   // [row][chunk^swz], chunk = 8 halves
    __shared__ f16 Bs[64 * 64];

    const int tid = threadIdx.x;
    const int w = tid >> 6, l = tid & 63;
    const int g = l >> 4, r = l & 15;

    const int m0 = blockIdx.x * 128;
    const int n0 = blockIdx.y * 64;
    const int mat = n0 >> 8;          // 0=Q 1=K 2=V
    const int ch0 = n0 & 255;

    const float* W    = (mat == 0) ? Wq : (mat == 1) ? Wk : Wv;
    const float* bias = (mat == 0) ? bq : (mat == 1) ? bk : bv;

    const int b  = m0 >> 11;          // 2048 % 128 == 0
    const int l0 = m0 & 2047;         // 1536 % 128 == 0 -> clean audio/text split

    f32x4 acc[2][4] = {};

    for (int k0 = 0; k0 < CC; k0 += 64) {
        #pragma unroll
        for (int m = 0; m < 4; ++m) {            // A: 128 rows x 8 chunks
            const int idx = m * 256 + tid;
            const int row = idx >> 3, c = idx & 7;
            const int lrow = l0 + row;
            const float* src = (lrow < LA)
                ? (audio + ((size_t)b * LA + lrow) * CC + k0 + c * 8)
                : (text  + ((size_t)b * LS + (lrow - LA)) * CC + k0 + c * 8);
            const float4 x0 = *(const float4*)src;
            const float4 x1 = *(const float4*)(src + 4);
            *(f16x8*)(As + row * 64 + ((c ^ (row & 7)) << 3)) = cvt8(x0, x1);
        }
        #pragma unroll
        for (int m = 0; m < 2; ++m) {            // W: 64 rows x 8 chunks
            const int idx = m * 256 + tid;
            const int row = idx >> 3, c = idx & 7;
            const float* src = W + (size_t)(ch0 + row) * CC + k0 + c * 8;
            const float4 x0 = *(const float4*)src;
            const float4 x1 = *(const float4*)(src + 4);
            *(f16x8*)(Bs + row * 64 + ((c ^ (row & 7)) << 3)) = cvt8(x0, x1);
        }
        __syncthreads();
        #pragma unroll
        for (int kc = 0; kc < 2; ++kc) {
            f16x8 af[2];
            #pragma unroll
            for (int i = 0; i < 2; ++i) {
                const int row = w * 32 + i * 16 + r;
                const int c = kc * 4 + g;
                af[i] = *(const f16x8*)(As + row * 64 + ((c ^ (row & 7)) << 3));
            }
            f16x8 bf[4];
            #pragma unroll
            for (int j = 0; j < 4; ++j) {
                const int row = j * 16 + r;
                const int c = kc * 4 + g;
                bf[j] = *(const f16x8*)(Bs + row * 64 + ((c ^ (row & 7)) << 3));
            }
            #pragma unroll
            for (int i = 0; i < 2; ++i)
                #pragma unroll
                for (int j = 0; j < 4; ++j)
                    acc[i][j] = __builtin_amdgcn_mfma_f32_16x16x32_f16(af[i], bf[j], acc[i][j], 0, 0, 0);
        }
        __syncthreads();
    }

    float bcol[4];
    #pragma unroll
    for (int j = 0; j < 4; ++j) bcol[j] = bias[ch0 + j * 16 + r];

    if (mat <= 1) {
        f16* Out = (mat == 0) ? Qh : Kh;
        #pragma unroll
        for (int i = 0; i < 2; ++i)
            #pragma unroll
            for (int e = 0; e < 4; ++e) {
                const int m = m0 + w * 32 + i * 16 + g * 4 + e;
                #pragma unroll
                for (int j = 0; j < 4; ++j)
                    Out[(size_t)m * CC + ch0 + j * 16 + r] = (_Float16)(acc[i][j][e] + bcol[j]);
            }
    } else {
        #pragma unroll
        for (int i = 0; i < 2; ++i)
            #pragma unroll
            for (int e = 0; e < 4; ++e) {
                const int m = m0 + w * 32 + i * 16 + g * 4 + e;
                const int b2 = m >> 11, ll = m & 2047;
                #pragma unroll
                for (int j = 0; j < 4; ++j) {
                    const int n = ch0 + j * 16 + r;
                    const int hh = n >> 6, dd = n & 63;
                    Vth[((size_t)(b2 * NH + hh) * DKH + dd) * LT + ll] =
                        (_Float16)(acc[i][j][e] + bcol[j]);
                }
            }
    }
}

// ---------------------------------------------------------------------------
// Kernel 2: flash attention, fp16 MFMA, inverted mask.
//   allowed(q,k): k<LA: k>=ilen ; k>=LA: (q<LA) || (k>q) || (k>=LA+ylen)
// Tiles with k0+64 <= ilen are fully masked -> SKIPPED entirely.
// Tile modes (block-uniform): 0 = no mask, 1 = audio boundary, 2 = text causal.
// Double-buffered K/V staging, 1 barrier/tile. Q pre-scaled by 0.125 (exact).
// Output AO in fp16.
// ---------------------------------------------------------------------------
__global__ __launch_bounds__(256) void attn_f16(
    const f16* __restrict__ Q, const f16* __restrict__ K,
    const f16* __restrict__ Vt,
    const int* __restrict__ slen, const int* __restrict__ tlen,
    f16* __restrict__ AO)
{
    __shared__ f16 Ks[2][4096];       // [key][d], swizzled
    __shared__ f16 Vts[2][4096];      // [d][key], swizzled
    __shared__ f16 Ps[4][16 * 72];    // per-wave P [q_local][kk], stride 72

    const int tid = threadIdx.x;
    const int w = tid >> 6;
    const int l = tid & 63;
    const int g = l >> 4;
    const int r = l & 15;

    const int q0 = blockIdx.x * 64;
    const int h  = blockIdx.y;
    const int b  = blockIdx.z;

    const int ilen = slen[b];
    const int kcap = LA + tlen[b];
    const int nskip = ilen >> 6;          // fully-masked audio tiles

    const int qrow = q0 + 16 * w + r;

    // Q fragment (pre-scaled by 1/sqrt(DK) = 0.125; exponent-only, fp16-exact)
    f16x8 qf[2];
    #pragma unroll
    for (int ch = 0; ch < 2; ++ch) {
        f16x8 q8 = *(const f16x8*)(Q + ((size_t)(b * LT) + qrow) * CC + h * DKH + ch * 32 + g * 8);
        #pragma unroll
        for (int e = 0; e < 8; ++e) q8[e] = q8[e] * (_Float16)0.125f;
        qf[ch] = q8;
    }

    // staging lanes: 2 x (row = idx>>3, c = idx&7)
    const int srow0 = tid >> 3,            sc0 = tid & 7;
    const int srow1 = (256 + tid) >> 3,    sc1 = tid & 7;
    const int sdst0 = srow0 * 64 + ((sc0 ^ (srow0 & 7)) << 3);
    const int sdst1 = srow1 * 64 + ((sc1 ^ (srow1 & 7)) << 3);

    // prologue: stage tile nskip into buffer 0
    {
        const int k0 = nskip * 64;
        *(f16x8*)(Ks[0] + sdst0) = *(const f16x8*)(K + ((size_t)(b * LT) + k0 + srow0) * CC + h * DKH + sc0 * 8);
        *(f16x8*)(Vts[0] + sdst0) = *(const f16x8*)(Vt + ((size_t)((b * NH + h) * DKH) + srow0) * LT + k0 + sc0 * 8);
        *(f16x8*)(Ks[0] + sdst1) = *(const f16x8*)(K + ((size_t)(b * LT) + k0 + srow1) * CC + h * DKH + sc1 * 8);
        *(f16x8*)(Vts[0] + sdst1) = *(const f16x8*)(Vt + ((size_t)((b * NH + h) * DKH) + srow1) * LT + k0 + sc1 * 8);
    }
    __syncthreads();

    float m_run = -INFINITY, l_run = 0.0f;
    f32x4 o[4] = {};   // o[dsb][e]: O[q = 4g+e][d = 16*dsb + r]

    int cur = 0;
    for (int kt = nskip; kt < NT; ++kt) {
        const int k0 = kt * 64;
        const bool have_next = (kt + 1 < NT);

        // issue next-tile global loads (overlap with compute below)
        f16x8 kr0, vr0, kr1, vr1;
        if (have_next) {
            const int kn = k0 + 64;
            kr0 = *(const f16x8*)(K + ((size_t)(b * LT) + kn + srow0) * CC + h * DKH + sc0 * 8);
            vr0 = *(const f16x8*)(Vt + ((size_t)((b * NH + h) * DKH) + srow0) * LT + kn + sc0 * 8);
            kr1 = *(const f16x8*)(K + ((size_t)(b * LT) + kn + srow1) * CC + h * DKH + sc1 * 8);
            vr1 = *(const f16x8*)(Vt + ((size_t)((b * NH + h) * DKH) + srow1) * LT + kn + sc1 * 8);
        }

        // ---- S^T = K · Q^T
        f32x4 sacc[4] = {};
        #pragma unroll
        for (int s = 0; s < 4; ++s) {
            const int row = 16 * s + r;
            #pragma unroll
            for (int ch = 0; ch < 2; ++ch) {
                const f16x8 a = *(const f16x8*)(Ks[cur] + row * 64 + ((((ch * 4 + g) ^ (row & 7)) & 7) << 3));
                sacc[s] = __builtin_amdgcn_mfma_f32_16x16x32_f16(a, qf[ch], sacc[s], 0, 0, 0);
            }
        }

        // ---- mask (block-uniform mode)
        const int mode = (kt < LA / 64) ? ((k0 >= ilen) ? 0 : 1)
                                        : ((q0 < LA) ? 0 : 2);
        float sv[16];
        if (mode == 0) {
            #pragma unroll
            for (int s = 0; s < 4; ++s)
                #pragma unroll
                for (int e = 0; e < 4; ++e) sv[s * 4 + e] = sacc[s][e];
        } else if (mode == 1) {
            #pragma unroll
            for (int s = 0; s < 4; ++s)
                #pragma unroll
                for (int e = 0; e < 4; ++e) {
                    const int kk = k0 + 16 * s + 4 * g + e;
                    sv[s * 4 + e] = (kk >= ilen) ? sacc[s][e] : -INFINITY;
                }
        } else {
            #pragma unroll
            for (int s = 0; s < 4; ++s)
                #pragma unroll
                for (int e = 0; e < 4; ++e) {
                    const int kk = k0 + 16 * s + 4 * g + e;
                    sv[s * 4 + e] = (kk > qrow || kk >= kcap) ? sacc[s][e] : -INFINITY;
                }
        }

        // ---- online softmax (no -inf special case: first tile always live)
        float mloc = -INFINITY;
        #pragma unroll
        for (int u = 0; u < 16; ++u) mloc = fmaxf(mloc, sv[u]);
        mloc = fmaxf(mloc, __shfl_xor(mloc, 16));
        mloc = fmaxf(mloc, __shfl_xor(mloc, 32));
        const float m_new = fmaxf(m_run, mloc);

        float ssum = 0.0f;
        f16x4 ph[4];
        #pragma unroll
        for (int s = 0; s < 4; ++s)
            #pragma unroll
            for (int e = 0; e < 4; ++e) {
                const float p = __expf(sv[s * 4 + e] - m_new);   // exp(-inf)=0
                ph[s][e] = (_Float16)p;
                ssum += p;
            }
        ssum += __shfl_xor(ssum, 16);
        ssum += __shfl_xor(ssum, 32);
        const float sc = __expf(m_run - m_new);                  // first iter: 0
        l_run = l_run * sc + ssum;
        m_run = m_new;

        // ---- P -> per-wave LDS re-layout
        #pragma unroll
        for (int s = 0; s < 4; ++s)
            *(f16x4*)(&Ps[w][0] + r * 72 + 16 * s + 4 * g) = ph[s];

        // ---- rescale O (broadcast sc to O layout q = 4g+e)
        #pragma unroll
        for (int e = 0; e < 4; ++e) {
            const float scr = __shfl(sc, 4 * g + e);
            #pragma unroll
            for (int dsb = 0; dsb < 4; ++dsb) o[dsb][e] *= scr;
        }

        // ---- O += P · V
        #pragma unroll
        for (int ch = 0; ch < 2; ++ch) {
            const f16x8 a = *(const f16x8*)(&Ps[w][0] + r * 72 + ch * 32 + g * 8);
            #pragma unroll
            for (int dsb = 0; dsb < 4; ++dsb) {
                const int vrow = 16 * dsb + r;
                const f16x8 bf = *(const f16x8*)(Vts[cur] + vrow * 64 + ((((ch * 4 + g) ^ (vrow & 7)) & 7) << 3));
                o[dsb] = __builtin_amdgcn_mfma_f32_16x16x32_f16(a, bf, o[dsb], 0, 0, 0);
            }
        }

        // ---- write staged next tile, single barrier
        if (have_next) {
            const int nxt = cur ^ 1;
            *(f16x8*)(Ks[nxt] + sdst0) = kr0;
            *(f16x8*)(Vts[nxt] + sdst0) = vr0;
            *(f16x8*)(Ks[nxt] + sdst1) = kr1;
            *(f16x8*)(Vts[nxt] + sdst1) = vr1;
        }
        __syncthreads();
        cur ^= 1;
    }

    // ---- epilogue
    const float linv = 1.0f / l_run;
    #pragma unroll
    for (int e = 0; e < 4; ++e) {
        const float inv = __shfl(linv, 4 * g + e);
        const int qq = q0 + 16 * w + 4 * g + e;
        #pragma unroll
        for (int dsb = 0; dsb < 4; ++dsb)
            AO[((size_t)(b * LT) + qq) * CC + h * DKH + 16 * dsb + r] =
                (_Float16)(o[dsb][e] * inv);
    }
}

// ---------------------------------------------------------------------------
// Kernel 3: output projection, fp16 MFMA (X already f16), fp32 out.
// ---------------------------------------------------------------------------
__global__ __launch_bounds__(256) void out_mfma(
    const f16* __restrict__ X, const float* __restrict__ Wo,
    const float* __restrict__ bo, float* __restrict__ Out)
{
    __shared__ f16 As[128 * 64];
    __shared__ f16 Bs[64 * 64];

    const int tid = threadIdx.x;
    const int w = tid >> 6, l = tid & 63;
    const int g = l >> 4, r = l & 15;

    const int m0 = blockIdx.x * 128;
    const int n0 = blockIdx.y * 64;

    f32x4 acc[2][4] = {};

    for (int k0 = 0; k0 < CC; k0 += 64) {
        #pragma unroll
        for (int m = 0; m < 4; ++m) {
            const int idx = m * 256 + tid;
            const int row = idx >> 3, c = idx & 7;
            *(f16x8*)(As + row * 64 + ((c ^ (row & 7)) << 3)) =
                *(const f16x8*)(X + (size_t)(m0 + row) * CC + k0 + c * 8);
        }
        #pragma unroll
        for (int m = 0; m < 2; ++m) {
            const int idx = m * 256 + tid;
            const int row = idx >> 3, c = idx & 7;
            const float* src = Wo + (size_t)(n0 + row) * CC + k0 + c * 8;
            const float4 x0 = *(const float4*)src;
            const float4 x1 = *(const float4*)(src + 4);
            *(f16x8*)(Bs + row * 64 + ((c ^ (row & 7)) << 3)) = cvt8(x0, x1);
        }
        __syncthreads();
        #pragma unroll
        for (int kc = 0; kc < 2; ++kc) {
            f16x8 af[2];
            #pragma unroll
            for (int i = 0; i < 2; ++i) {
                const int row = w * 32 + i * 16 + r;
                const int c = kc * 4 + g;
                af[i] = *(const f16x8*)(As + row * 64 + ((c ^ (row & 7)) << 3));
            }
            f16x8 bf[4];
            #pragma unroll
            for (int j = 0; j < 4; ++j) {
                const int row = j * 16 + r;
                const int c = kc * 4 + g;
                bf[j] = *(const f16x8*)(Bs + row * 64 + ((c ^ (row & 7)) << 3));
            }
            #pragma unroll
            for (int i = 0; i < 2; ++i)
                #pragma unroll
                for (int j = 0; j < 4; ++j)
                    acc[i][j] = __builtin_amdgcn_mfma_f32_16x16x32_f16(af[i], bf[j], acc[i][j], 0, 0, 0);
        }
        __syncthreads();
    }

    float bcol[4];
    #pragma unroll
    for (int j = 0; j < 4; ++j) bcol[j] = bo[n0 + j * 16 + r];

    #pragma unroll
    for (int i = 0; i < 2; ++i)
        #pragma unroll
        for (int e = 0; e < 4; ++e) {
            const int m = m0 + w * 32 + i * 16 + g * 4 + e;
            #pragma unroll
            for (int j = 0; j < 4; ++j)
                Out[(size_t)m * CC + n0 + j * 16 + r] = acc[i][j][e] + bcol[j];
        }
}

// ---------------------------------------------------------------------------
extern "C" void kernel_launch(void* const* d_in, const int* in_sizes, int n_in,
                              void* d_out, int out_size, void* d_ws, size_t ws_size,
                              hipStream_t stream)
{
    const float* audio = (const float*)d_in[0];
    const float* text  = (const float*)d_in[1];
    const int*   slen  = (const int*)d_in[2];
    const int*   tlen  = (const int*)d_in[3];
    const float* Wq = (const float*)d_in[4];
    const float* bq = (const float*)d_in[5];
    const float* Wk = (const float*)d_in[6];
    const float* bk = (const float*)d_in[7];
    const float* Wv = (const float*)d_in[8];
    const float* bv = (const float*)d_in[9];
    const float* Wo = (const float*)d_in[10];
    const float* bo = (const float*)d_in[11];
    float* out = (float*)d_out;

    // workspace: Qh,Kh,Vth,AOh f16 (4 MB each)
    const size_t SZ = (size_t)NB * LT * CC;
    f16* Qh  = (f16*)d_ws;
    f16* Kh  = Qh + SZ;
    f16* Vth = Kh + SZ;
    f16* AOh = Vth + SZ;

    qkv_mfma<<<dim3(64, 12), 256, 0, stream>>>(audio, text, Wq, bq, Wk, bk, Wv, bv,
                                               Qh, Kh, Vth);
    attn_f16<<<dim3(LT / 64, NH, NB), 256, 0, stream>>>(Qh, Kh, Vth, slen, tlen, AOh);
    out_mfma<<<dim3(64, 4), 256, 0, stream>>>(AOh, Wo, bo, out);
}

// Round 4
// 49.301 us; speedup vs baseline: 7.7758x; 1.0967x over previous
//
#include <hip/hip_runtime.h>
#include <hip/hip_bf16.h>
#include <math.h>

#define LA 1536
#define LS 512
#define LT 2048
#define CC 256
#define NH 4
#define DKH 64
#define NB 4
#define NT (LT / 64)
#define NTA (LA / 64)   // 24 audio tiles

typedef _Float16 f16;
typedef __attribute__((ext_vector_type(8))) _Float16 f16x8;
typedef __attribute__((ext_vector_type(4))) _Float16 f16x4;
typedef __attribute__((ext_vector_type(4))) float f32x4;

__device__ inline f16x8 cvt8(const float4 a, const float4 b) {
    f16x8 h;
    h[0] = (_Float16)a.x; h[1] = (_Float16)a.y; h[2] = (_Float16)a.z; h[3] = (_Float16)a.w;
    h[4] = (_Float16)b.x; h[5] = (_Float16)b.y; h[6] = (_Float16)b.z; h[7] = (_Float16)b.w;
    return h;
}

// ---------------------------------------------------------------------------
// Kernel 1: fused QKV projection, fp16 MFMA, fp32 accumulate.
// Q,K row-major f16; V transposed Vt[(b*NH+h)*DKH+d][l] via LDS transpose
// (round-3 wrote Vt with scalar 2B scatters - uncoalesced).
// ---------------------------------------------------------------------------
__global__ __launch_bounds__(256) void qkv_mfma(
    const float* __restrict__ audio, const float* __restrict__ text,
    const float* __restrict__ Wq, const float* __restrict__ bq,
    const float* __restrict__ Wk, const float* __restrict__ bk,
    const float* __restrict__ Wv, const float* __restrict__ bv,
    f16* __restrict__ Qh, f16* __restrict__ Kh, f16* __restrict__ Vth)
{
    __shared__ f16 smem[128 * 64 + 64 * 64];   // As | Bs ; reused as Ts for V
    f16* As = smem;
    f16* Bs = smem + 128 * 64;

    const int tid = threadIdx.x;
    const int w = tid >> 6, l = tid & 63;
    const int g = l >> 4, r = l & 15;

    const int m0 = blockIdx.x * 128;
    const int n0 = blockIdx.y * 64;
    const int mat = n0 >> 8;          // 0=Q 1=K 2=V
    const int ch0 = n0 & 255;

    const float* W    = (mat == 0) ? Wq : (mat == 1) ? Wk : Wv;
    const float* bias = (mat == 0) ? bq : (mat == 1) ? bk : bv;

    const int b  = m0 >> 11;
    const int l0 = m0 & 2047;         // 1536 % 128 == 0 -> clean split

    f32x4 acc[2][4] = {};

    for (int k0 = 0; k0 < CC; k0 += 64) {
        #pragma unroll
        for (int m = 0; m < 4; ++m) {
            const int idx = m * 256 + tid;
            const int row = idx >> 3, c = idx & 7;
            const int lrow = l0 + row;
            const float* src = (lrow < LA)
                ? (audio + ((size_t)b * LA + lrow) * CC + k0 + c * 8)
                : (text  + ((size_t)b * LS + (lrow - LA)) * CC + k0 + c * 8);
            const float4 x0 = *(const float4*)src;
            const float4 x1 = *(const float4*)(src + 4);
            *(f16x8*)(As + row * 64 + ((c ^ (row & 7)) << 3)) = cvt8(x0, x1);
        }
        #pragma unroll
        for (int m = 0; m < 2; ++m) {
            const int idx = m * 256 + tid;
            const int row = idx >> 3, c = idx & 7;
            const float* src = W + (size_t)(ch0 + row) * CC + k0 + c * 8;
            const float4 x0 = *(const float4*)src;
            const float4 x1 = *(const float4*)(src + 4);
            *(f16x8*)(Bs + row * 64 + ((c ^ (row & 7)) << 3)) = cvt8(x0, x1);
        }
        __syncthreads();
        #pragma unroll
        for (int kc = 0; kc < 2; ++kc) {
            f16x8 af[2];
            #pragma unroll
            for (int i = 0; i < 2; ++i) {
                const int row = w * 32 + i * 16 + r;
                const int c = kc * 4 + g;
                af[i] = *(const f16x8*)(As + row * 64 + ((c ^ (row & 7)) << 3));
            }
            f16x8 bf[4];
            #pragma unroll
            for (int j = 0; j < 4; ++j) {
                const int row = j * 16 + r;
                const int c = kc * 4 + g;
                bf[j] = *(const f16x8*)(Bs + row * 64 + ((c ^ (row & 7)) << 3));
            }
            #pragma unroll
            for (int i = 0; i < 2; ++i)
                #pragma unroll
                for (int j = 0; j < 4; ++j)
                    acc[i][j] = __builtin_amdgcn_mfma_f32_16x16x32_f16(af[i], bf[j], acc[i][j], 0, 0, 0);
        }
        __syncthreads();
    }

    float bcol[4];
    #pragma unroll
    for (int j = 0; j < 4; ++j) bcol[j] = bias[ch0 + j * 16 + r];

    if (mat <= 1) {
        f16* Out = (mat == 0) ? Qh : Kh;
        #pragma unroll
        for (int i = 0; i < 2; ++i)
            #pragma unroll
            for (int e = 0; e < 4; ++e) {
                const int m = m0 + w * 32 + i * 16 + g * 4 + e;
                #pragma unroll
                for (int j = 0; j < 4; ++j)
                    Out[(size_t)m * CC + ch0 + j * 16 + r] = (_Float16)(acc[i][j][e] + bcol[j]);
            }
    } else {
        // V: stage C^T in LDS (Ts[64 n][136 m-pad]), then coalesced vec8 store.
        f16* Ts = smem;   // 64*136 = 8704 f16 <= 12288, As/Bs dead after loop
        #pragma unroll
        for (int i = 0; i < 2; ++i)
            #pragma unroll
            for (int e = 0; e < 4; ++e) {
                const int ml = w * 32 + i * 16 + g * 4 + e;
                #pragma unroll
                for (int j = 0; j < 4; ++j)
                    Ts[(j * 16 + r) * 136 + ml] = (_Float16)(acc[i][j][e] + bcol[j]);
            }
        __syncthreads();
        const int b2 = m0 >> 11, l0m = m0 & 2047;
        #pragma unroll
        for (int u = 0; u < 4; ++u) {
            const int idx = u * 256 + tid;
            const int nl = idx >> 4, mc = idx & 15;
            const f16x8 vv = *(const f16x8*)(Ts + nl * 136 + mc * 8);
            const int nglob = ch0 + nl;
            const int hh = nglob >> 6, dd = nglob & 63;
            *(f16x8*)(Vth + ((size_t)((b2 * NH + hh) * DKH + dd)) * LT + l0m + mc * 8) = vv;
        }
    }
}

// ---------------------------------------------------------------------------
// Kernel 2: flash attention, fp16 MFMA, inverted mask, WITHIN-BLOCK SPLIT-K.
//   allowed(q,k): k<LA: k>=ilen ; k>=LA: (q<LA) || (k>q) || (k>=LA+ylen)
// 8 waves: group 0 (waves 0-3) even live tiles, group 1 (waves 4-7) odd.
// Per-group single K/V LDS buffer + register-staged next tile (T14).
// Skips: fully-masked audio tiles (k0+64<=ilen) and, for text-q blocks,
// below-diagonal-and-below-kcap text tiles (a prefix of the text region).
// Partial (m,l,o) combined through LDS. Sentinel m=-1e30 keeps math NaN-free.
// ---------------------------------------------------------------------------
__global__ __launch_bounds__(512) void attn_f16(
    const f16* __restrict__ Q, const f16* __restrict__ K,
    const f16* __restrict__ Vt,
    const int* __restrict__ slen, const int* __restrict__ tlen,
    f16* __restrict__ AO)
{
    __shared__ f16 Ks[2][4096];       // [group][key*64+d'], swizzled
    __shared__ f16 Vts[2][4096];      // [group][d*64+key'], swizzled
    __shared__ f16 Ps[8][16 * 72];    // per-wave P
    __shared__ float Oc[4][1024];     // group-1 o: [wg][dsb*256 + lane*4 + e]
    __shared__ float ML[2][64][2];    // [group][q_local][m,l]

    const int tid = threadIdx.x;
    const int w = tid >> 6, l = tid & 63;
    const int gid = w >> 2, wg = w & 3;
    const int g = l >> 4, r = l & 15;
    const int tg = tid & 255;         // id within group

    const int q0 = blockIdx.x * 64;
    const int h  = blockIdx.y;
    const int b  = blockIdx.z;

    const int ilen = slen[b];
    const int kcap = LA + tlen[b];
    const int nskip = ilen >> 6;
    int ntskip = 0;
    if (q0 >= LA) {
        const int skipmax = min(q0 - 63, kcap - 64);
        const int d = skipmax - LA;
        ntskip = (d < 0) ? 0 : ((d >> 6) + 1);
    }
    const int nAudio = NTA - nskip;               // >= 1
    const int nProc  = nAudio + (NT - NTA) - ntskip;
    const int nIter  = (nProc + 1) >> 1;

    const int qrow = q0 + 16 * wg + r;

    // Q fragment, pre-scaled by 1/8 (exact)
    f16x8 qf[2];
    #pragma unroll
    for (int ch = 0; ch < 2; ++ch) {
        f16x8 q8 = *(const f16x8*)(Q + ((size_t)(b * LT) + qrow) * CC + h * DKH + ch * 32 + g * 8);
        #pragma unroll
        for (int e = 0; e < 8; ++e) q8[e] = q8[e] * (_Float16)0.125f;
        qf[ch] = q8;
    }

    // staging (per group: 256 threads, 2 rows x vec8 each for K and V)
    const int srow0 = tg >> 3, scc = tg & 7;
    const int srow1 = srow0 + 32;
    const int sdst0 = srow0 * 64 + ((scc ^ (srow0 & 7)) << 3);
    const int sdst1 = srow1 * 64 + ((scc ^ (srow1 & 7)) << 3);

    #define TILE_OF(p) ((p) < nAudio ? (nskip + (p)) : (NTA + ntskip + ((p) - nAudio)))

    // prologue: stage this group's first tile (pidx = gid, always valid)
    {
        const int k0 = TILE_OF(gid) * 64;
        *(f16x8*)(Ks[gid] + sdst0)  = *(const f16x8*)(K  + ((size_t)(b * LT) + k0 + srow0) * CC + h * DKH + scc * 8);
        *(f16x8*)(Vts[gid] + sdst0) = *(const f16x8*)(Vt + ((size_t)((b * NH + h) * DKH) + srow0) * LT + k0 + scc * 8);
        *(f16x8*)(Ks[gid] + sdst1)  = *(const f16x8*)(K  + ((size_t)(b * LT) + k0 + srow1) * CC + h * DKH + scc * 8);
        *(f16x8*)(Vts[gid] + sdst1) = *(const f16x8*)(Vt + ((size_t)((b * NH + h) * DKH) + srow1) * LT + k0 + scc * 8);
    }

    float m_run = -1e30f, l_run = 0.0f;
    f32x4 o[4] = {};

    for (int i = 0; i < nIter; ++i) {
        __syncthreads();                       // A: LDS tiles for iter i visible
        const int pcur = 2 * i + gid;
        const bool curV = pcur < nProc;
        const bool nxtV = (pcur + 2) < nProc;

        f16x8 kr0, vr0, kr1, vr1;
        if (nxtV) {                            // issue next-tile loads early
            const int kn = TILE_OF(pcur + 2) * 64;
            kr0 = *(const f16x8*)(K  + ((size_t)(b * LT) + kn + srow0) * CC + h * DKH + scc * 8);
            vr0 = *(const f16x8*)(Vt + ((size_t)((b * NH + h) * DKH) + srow0) * LT + kn + scc * 8);
            kr1 = *(const f16x8*)(K  + ((size_t)(b * LT) + kn + srow1) * CC + h * DKH + scc * 8);
            vr1 = *(const f16x8*)(Vt + ((size_t)((b * NH + h) * DKH) + srow1) * LT + kn + scc * 8);
        }

        if (curV) {
            const int kt = TILE_OF(pcur);
            const int k0 = kt * 64;

            // ---- S^T = K . Q^T
            f32x4 sacc[4] = {};
            #pragma unroll
            for (int s = 0; s < 4; ++s) {
                const int row = 16 * s + r;
                #pragma unroll
                for (int ch = 0; ch < 2; ++ch) {
                    const f16x8 a = *(const f16x8*)(Ks[gid] + row * 64 + ((((ch * 4 + g) ^ (row & 7)) & 7) << 3));
                    sacc[s] = __builtin_amdgcn_mfma_f32_16x16x32_f16(a, qf[ch], sacc[s], 0, 0, 0);
                }
            }

            // ---- mask (block-uniform mode)
            const int mode = (kt < NTA) ? ((k0 >= ilen) ? 0 : 1)
                                        : ((q0 < LA) ? 0 : 2);
            float sv[16];
            if (mode == 0) {
                #pragma unroll
                for (int s = 0; s < 4; ++s)
                    #pragma unroll
                    for (int e = 0; e < 4; ++e) sv[s * 4 + e] = sacc[s][e];
            } else if (mode == 1) {
                #pragma unroll
                for (int s = 0; s < 4; ++s)
                    #pragma unroll
                    for (int e = 0; e < 4; ++e) {
                        const int kk = k0 + 16 * s + 4 * g + e;
                        sv[s * 4 + e] = (kk >= ilen) ? sacc[s][e] : -INFINITY;
                    }
            } else {
                #pragma unroll
                for (int s = 0; s < 4; ++s)
                    #pragma unroll
                    for (int e = 0; e < 4; ++e) {
                        const int kk = k0 + 16 * s + 4 * g + e;
                        sv[s * 4 + e] = (kk > qrow || kk >= kcap) ? sacc[s][e] : -INFINITY;
                    }
            }

            // ---- online softmax (finite sentinel: no -inf special case)
            float mloc = -1e30f;
            #pragma unroll
            for (int u = 0; u < 16; ++u) mloc = fmaxf(mloc, sv[u]);
            mloc = fmaxf(mloc, __shfl_xor(mloc, 16));
            mloc = fmaxf(mloc, __shfl_xor(mloc, 32));
            const float m_new = fmaxf(m_run, mloc);

            float ssum = 0.0f;
            f16x4 ph[4];
            #pragma unroll
            for (int s = 0; s < 4; ++s)
                #pragma unroll
                for (int e = 0; e < 4; ++e) {
                    const float p = __expf(sv[s * 4 + e] - m_new);
                    ph[s][e] = (_Float16)p;
                    ssum += p;
                }
            ssum += __shfl_xor(ssum, 16);
            ssum += __shfl_xor(ssum, 32);
            const float sc = __expf(m_run - m_new);
            l_run = l_run * sc + ssum;
            m_run = m_new;

            // ---- P -> per-wave LDS re-layout
            #pragma unroll
            for (int s = 0; s < 4; ++s)
                *(f16x4*)(&Ps[w][0] + r * 72 + 16 * s + 4 * g) = ph[s];

            // ---- rescale O
            #pragma unroll
            for (int e = 0; e < 4; ++e) {
                const float scr = __shfl(sc, 4 * g + e);
                #pragma unroll
                for (int dsb = 0; dsb < 4; ++dsb) o[dsb][e] *= scr;
            }

            // ---- O += P . V
            #pragma unroll
            for (int ch = 0; ch < 2; ++ch) {
                const f16x8 a = *(const f16x8*)(&Ps[w][0] + r * 72 + ch * 32 + g * 8);
                #pragma unroll
                for (int dsb = 0; dsb < 4; ++dsb) {
                    const int vrow = 16 * dsb + r;
                    const f16x8 bf = *(const f16x8*)(Vts[gid] + vrow * 64 + ((((ch * 4 + g) ^ (vrow & 7)) & 7) << 3));
                    o[dsb] = __builtin_amdgcn_mfma_f32_16x16x32_f16(a, bf, o[dsb], 0, 0, 0);
                }
            }
        }

        __syncthreads();                       // B: group's LDS reads done
        if (nxtV) {
            *(f16x8*)(Ks[gid] + sdst0)  = kr0;
            *(f16x8*)(Vts[gid] + sdst0) = vr0;
            *(f16x8*)(Ks[gid] + sdst1)  = kr1;
            *(f16x8*)(Vts[gid] + sdst1) = vr1;
        }
    }

    // ---- combine the two groups' partials
    if (g == 0) {                              // m/l uniform across g per (wg,r)
        ML[gid][16 * wg + r][0] = m_run;
        ML[gid][16 * wg + r][1] = l_run;
    }
    if (gid == 1) {
        #pragma unroll
        for (int dsb = 0; dsb < 4; ++dsb)
            *(f32x4*)&Oc[wg][dsb * 256 + (g * 16 + r) * 4] = o[dsb];
    }
    __syncthreads();

    if (gid == 0) {
        #pragma unroll
        for (int e = 0; e < 4; ++e) {
            const int qloc = 16 * wg + 4 * g + e;
            const float m0v = ML[0][qloc][0], l0v = ML[0][qloc][1];
            const float m1v = ML[1][qloc][0], l1v = ML[1][qloc][1];
            const float mt = fmaxf(m0v, m1v);
            const float c0 = __expf(m0v - mt);
            const float c1 = __expf(m1v - mt);
            const float inv = 1.0f / (l0v * c0 + l1v * c1);
            const int qq = q0 + qloc;
            #pragma unroll
            for (int dsb = 0; dsb < 4; ++dsb) {
                const float of = (o[dsb][e] * c0 + Oc[wg][dsb * 256 + (g * 16 + r) * 4 + e] * c1) * inv;
                AO[((size_t)(b * LT) + qq) * CC + h * DKH + 16 * dsb + r] = (_Float16)of;
            }
        }
    }
    #undef TILE_OF
}

// ---------------------------------------------------------------------------
// Kernel 3: output projection, fp16 MFMA (X already f16), fp32 out.
// ---------------------------------------------------------------------------
__global__ __launch_bounds__(256) void out_mfma(
    const f16* __restrict__ X, const float* __restrict__ Wo,
    const float* __restrict__ bo, float* __restrict__ Out)
{
    __shared__ f16 As[128 * 64];
    __shared__ f16 Bs[64 * 64];

    const int tid = threadIdx.x;
    const int w = tid >> 6, l = tid & 63;
    const int g = l >> 4, r = l & 15;

    const int m0 = blockIdx.x * 128;
    const int n0 = blockIdx.y * 64;

    f32x4 acc[2][4] = {};

    for (int k0 = 0; k0 < CC; k0 += 64) {
        #pragma unroll
        for (int m = 0; m < 4; ++m) {
            const int idx = m * 256 + tid;
            const int row = idx >> 3, c = idx & 7;
            *(f16x8*)(As + row * 64 + ((c ^ (row & 7)) << 3)) =
                *(const f16x8*)(X + (size_t)(m0 + row) * CC + k0 + c * 8);
        }
        #pragma unroll
        for (int m = 0; m < 2; ++m) {
            const int idx = m * 256 + tid;
            const int row = idx >> 3, c = idx & 7;
            const float* src = Wo + (size_t)(n0 + row) * CC + k0 + c * 8;
            const float4 x0 = *(const float4*)src;
            const float4 x1 = *(const float4*)(src + 4);
            *(f16x8*)(Bs + row * 64 + ((c ^ (row & 7)) << 3)) = cvt8(x0, x1);
        }
        __syncthreads();
        #pragma unroll
        for (int kc = 0; kc < 2; ++kc) {
            f16x8 af[2];
            #pragma unroll
            for (int i = 0; i < 2; ++i) {
                const int row = w * 32 + i * 16 + r;
                const int c = kc * 4 + g;
                af[i] = *(const f16x8*)(As + row * 64 + ((c ^ (row & 7)) << 3));
            }
            f16x8 bf[4];
            #pragma unroll
            for (int j = 0; j < 4; ++j) {
                const int row = j * 16 + r;
                const int c = kc * 4 + g;
                bf[j] = *(const f16x8*)(Bs + row * 64 + ((c ^ (row & 7)) << 3));
            }
            #pragma unroll
            for (int i = 0; i < 2; ++i)
                #pragma unroll
                for (int j = 0; j < 4; ++j)
                    acc[i][j] = __builtin_amdgcn_mfma_f32_16x16x32_f16(af[i], bf[j], acc[i][j], 0, 0, 0);
        }
        __syncthreads();
    }

    float bcol[4];
    #pragma unroll
    for (int j = 0; j < 4; ++j) bcol[j] = bo[n0 + j * 16 + r];

    #pragma unroll
    for (int i = 0; i < 2; ++i)
        #pragma unroll
        for (int e = 0; e < 4; ++e) {
            const int m = m0 + w * 32 + i * 16 + g * 4 + e;
            #pragma unroll
            for (int j = 0; j < 4; ++j)
                Out[(size_t)m * CC + n0 + j * 16 + r] = acc[i][j][e] + bcol[j];
        }
}

// ---------------------------------------------------------------------------
extern "C" void kernel_launch(void* const* d_in, const int* in_sizes, int n_in,
                              void* d_out, int out_size, void* d_ws, size_t ws_size,
                              hipStream_t stream)
{
    const float* audio = (const float*)d_in[0];
    const float* text  = (const float*)d_in[1];
    const int*   slen  = (const int*)d_in[2];
    const int*   tlen  = (const int*)d_in[3];
    const float* Wq = (const float*)d_in[4];
    const float* bq = (const float*)d_in[5];
    const float* Wk = (const float*)d_in[6];
    const float* bk = (const float*)d_in[7];
    const float* Wv = (const float*)d_in[8];
    const float* bv = (const float*)d_in[9];
    const float* Wo = (const float*)d_in[10];
    const float* bo = (const float*)d_in[11];
    float* out = (float*)d_out;

    const size_t SZ = (size_t)NB * LT * CC;
    f16* Qh  = (f16*)d_ws;
    f16* Kh  = Qh + SZ;
    f16* Vth = Kh + SZ;
    f16* AOh = Vth + SZ;

    qkv_mfma<<<dim3(64, 12), 256, 0, stream>>>(audio, text, Wq, bq, Wk, bk, Wv, bv,
                                               Qh, Kh, Vth);
    attn_f16<<<dim3(LT / 64, NH, NB), 512, 0, stream>>>(Qh, Kh, Vth, slen, tlen, AOh);
    out_mfma<<<dim3(64, 4), 256, 0, stream>>>(AOh, Wo, bo, out);
}